// Round 1
// baseline (217.770 us; speedup 1.0000x reference)
//
#include <hip/hip_runtime.h>

#define TLEN 512
#define HID  64

typedef _Float16 half8 __attribute__((ext_vector_type(8)));
typedef float    f32x4 __attribute__((ext_vector_type(4)));

__device__ __forceinline__ float rcp_fast(float x) { return __builtin_amdgcn_rcpf(x); }
__device__ __forceinline__ float exp2_fast(float x) {
#if __has_builtin(__builtin_amdgcn_exp2f)
    return __builtin_amdgcn_exp2f(x);
#else
    float r; asm("v_exp_f32 %0, %1" : "=v"(r) : "v"(x)); return r;
#endif
}

// R12: barrier-latency attack. R11 (174 us) had 1 block/CU: both waves per
// SIMD share one barrier -> ~40% dead time (817 cyc/step vs ~480 issue).
// Reshape: 512 blocks x 256 thr (4 waves), block owns 4 batch rows
// (16 MFMA cols = 4 real x 4 dup), wave owns 16 units as 4 A-tiles.
// Census invariant kept: 512*256 lanes = B*H -> exactly 1 act/lane, so
// per-SIMD activation issue unchanged; but each SIMD now hosts waves from
// TWO independent blocks -> uncorrelated barriers fill the stall.
// MFMA chained-accumulate again (4 indep chains): latency is hidden by the
// sibling block; issue count beats chain latency in this regime.
// hbuf stride 72->80: h-write and b128 h-read both hit 32 distinct banks.
__global__ __launch_bounds__(256) __attribute__((amdgpu_waves_per_eu(2, 2)))
void lstm_mfma4(const float* __restrict__ x,
                const float* __restrict__ W_ih,
                const float* __restrict__ W_hh,
                const float* __restrict__ b_ih,
                const float* __restrict__ b_hh,
                const float* __restrict__ W_d,
                const float* __restrict__ b_d,
                float* __restrict__ out) {
    __shared__ __align__(16) float    xs[4][516];     // 4 x rows
    __shared__ __align__(16) _Float16 hbuf[2][4][80]; // ping-pong h, pad 80

    const int tid = threadIdx.x;
    const int L   = tid & 63;
    const int w   = tid >> 6;        // wave 0..3, owns units [16w, 16w+16)
    const int r0  = blockIdx.x * 4;

    // ---- stage x rows (float4) ----
    for (int i = tid; i < 4 * 128; i += 256) {
        const int r = i >> 7, t4 = (i & 127) * 4;
        *(float4*)&xs[r][t4] = *(const float4*)&x[(size_t)(r0 + r) * TLEN + t4];
    }
    // ---- zero both h buffers (h0 = 0) ----
    for (int i = tid; i < 2 * 4 * 80; i += 256)
        ((_Float16*)hbuf)[i] = (_Float16)0.0f;

    // ---- resident A-frags: A[m][k], m=L&15, k=32q+(L>>4)*8+i ----
    // tile tt -> unit 16w+4tt+(m>>2), gate m&3 (i,f,g,o)
    half8 af[4][2];
    {
        const int m  = L & 15;
        const int g  = m & 3;
        const int kb = (L >> 4) * 8;
#pragma unroll
        for (int tt = 0; tt < 4; ++tt) {
            const int uu = 16 * w + 4 * tt + (m >> 2);
            const float* row = &W_hh[(size_t)(g * HID + uu) * HID];
#pragma unroll
            for (int q = 0; q < 2; ++q) {
                const float* p = row + 32 * q + kb;
                half8 hf;
#pragma unroll
                for (int i = 0; i < 8; ++i) hf[i] = (_Float16)p[i];
                af[tt][q] = hf;
            }
        }
    }

    // ---- lane role: col c, batch b (4 real rows), 2-bit dup selects tile ----
    const int c   = L & 15;
    const int b   = c & 3;
    const int dup = c >> 2;                  // 0..3
    const int u   = 16 * w + 4 * dup + (L >> 4);
    const bool d1 = dup & 1;
    const bool d2 = dup & 2;
    // 64 lanes <-> 64 distinct (b,u): exactly one activation per lane.

    // exp2-domain gate params: sigmoid arg -K*a, tanh arg +2K*a (K=log2 e)
    const float K = 1.44269504f;
    float wih[4], bias[4], dscl[4];
#pragma unroll
    for (int g = 0; g < 4; ++g) {
        const float s = (g == 2) ? 2.0f * K : -K;
        wih[g]  = s * W_ih[g * HID + u];
        bias[g] = s * (b_ih[g * HID + u] + b_hh[g * HID + u]);
        dscl[g] = s;
    }

    const float* xrow = &xs[b][0];
    const int koff = (L >> 4) * 8;
    const _Float16* h0r = &hbuf[0][b][0];
    _Float16*       h0w = &hbuf[0][0][0];
    const _Float16* h1r = &hbuf[1][b][0];
    _Float16*       h1w = &hbuf[1][0][0];
    const int widx = b * 80 + u;     // write offset within a buffer
    const f32x4 zero = {0.0f, 0.0f, 0.0f, 0.0f};
    float cst = 0.0f;

    __syncthreads();

    auto step = [&](const _Float16* hin, _Float16* hout, float xt) {
        // pre-gates: ready before MFMA results are consumed
        const float pre0 = fmaf(xt, wih[0], bias[0]);
        const float pre1 = fmaf(xt, wih[1], bias[1]);
        const float pre2 = fmaf(xt, wih[2], bias[2]);
        const float pre3 = fmaf(xt, wih[3], bias[3]);

        half8 b0 = *(const half8*)(hin + koff);
        half8 b1 = *(const half8*)(hin + koff + 32);

        // 4 independent chained-accumulate MFMAs (K=64 per tile)
        f32x4 t0 = __builtin_amdgcn_mfma_f32_16x16x32_f16(af[0][0], b0, zero, 0, 0, 0);
        f32x4 t1 = __builtin_amdgcn_mfma_f32_16x16x32_f16(af[1][0], b0, zero, 0, 0, 0);
        f32x4 t2 = __builtin_amdgcn_mfma_f32_16x16x32_f16(af[2][0], b0, zero, 0, 0, 0);
        f32x4 t3 = __builtin_amdgcn_mfma_f32_16x16x32_f16(af[3][0], b0, zero, 0, 0, 0);
        t0 = __builtin_amdgcn_mfma_f32_16x16x32_f16(af[0][1], b1, t0, 0, 0, 0);
        t1 = __builtin_amdgcn_mfma_f32_16x16x32_f16(af[1][1], b1, t1, 0, 0, 0);
        t2 = __builtin_amdgcn_mfma_f32_16x16x32_f16(af[2][1], b1, t2, 0, 0, 0);
        t3 = __builtin_amdgcn_mfma_f32_16x16x32_f16(af[3][1], b1, t3, 0, 0, 0);

        // 2-bit tile select (12 cndmask)
        f32x4 dS;
#pragma unroll
        for (int r = 0; r < 4; ++r) {
            const float a01 = d1 ? t1[r] : t0[r];
            const float a23 = d1 ? t3[r] : t2[r];
            dS[r] = d2 ? a23 : a01;
        }

        const float ei = exp2_fast(fmaf(dS[0], dscl[0], pre0));
        const float ef = exp2_fast(fmaf(dS[1], dscl[1], pre1));
        const float eg = exp2_fast(fmaf(dS[2], dscl[2], pre2));
        const float eo = exp2_fast(fmaf(dS[3], dscl[3], pre3));
        const float gi = rcp_fast(1.0f + ei);                    // sigmoid(i)
        const float gf = rcp_fast(1.0f + ef);                    // sigmoid(f)
        const float gg = fmaf(-2.0f, rcp_fast(1.0f + eg), 1.0f); // tanh(g)
        const float go = rcp_fast(1.0f + eo);                    // sigmoid(o)
        cst = fmaf(gf, cst, gi * gg);
        const float tc = fmaf(-2.0f, rcp_fast(1.0f + exp2_fast(2.0f * K * cst)), 1.0f);
        hout[widx] = (_Float16)(go * tc);  // one write per lane, 64 unique (b,u)
    };

    for (int t = 0; t < TLEN; t += 4) {
        // x register-blocking: one b128 read covers 4 steps (16B-aligned)
        const float4 xq = *(const float4*)&xrow[t];
        step(h0r, h1w, xq.x);
        __syncthreads();
        step(h1r, h0w, xq.y);
        __syncthreads();
        step(h0r, h1w, xq.z);
        __syncthreads();
        step(h1r, h0w, xq.w);
        __syncthreads();
    }

    // ---- epilogue: wave w reduces batch row w (final h in hbuf[0]) ----
    float pv = (float)hbuf[0][w][L] * W_d[L];
#pragma unroll
    for (int off = 32; off > 0; off >>= 1)
        pv += __shfl_xor(pv, off, 64);
    if (L == 0)
        out[r0 + w] = pv + b_d[0];
}

extern "C" void kernel_launch(void* const* d_in, const int* in_sizes, int n_in,
                              void* d_out, int out_size, void* d_ws, size_t ws_size,
                              hipStream_t stream) {
    const float* x    = (const float*)d_in[0];
    const float* W_ih = (const float*)d_in[1];
    const float* W_hh = (const float*)d_in[2];
    const float* b_ih = (const float*)d_in[3];
    const float* b_hh = (const float*)d_in[4];
    const float* W_d  = (const float*)d_in[5];
    const float* b_d  = (const float*)d_in[6];
    float* out = (float*)d_out;

    dim3 grid(512);    // 2048 / 4 batch rows per block -> 2 blocks/CU
    dim3 block(256);   // 4 waves; SIMD hosts waves of 2 INDEPENDENT blocks
    lstm_mfma4<<<grid, block, 0, stream>>>(x, W_ih, W_hh, b_ih, b_hh, W_d, b_d, out);
}